// Round 6
// baseline (285.145 us; speedup 1.0000x reference)
//
#include <hip/hip_runtime.h>
#include <hip/hip_bf16.h>

// FusionRetrModel: B=4, NL=2 (only l=1 used), P=100, TOK=60, T=6000, D=768.
// R6 pipeline:
//   prep_all (one dispatch): Qpad bf16 [4][6144][768]; Bcat=[Wpb;Wtb];
//         Wf1 bf16; cp/ct wide GEMV; out init = bf2*msum.
//   gemm12: [ps|ts] = Qpad @ Bcat^T + [cp|ct]   (256^2 8-wave 4-phase MFMA)
//   tmax:   per-table max over passages (tmax aliases dead Qpad region)
//   gemm3s: H = [ps | tmax-gather] @ Wf1^T, fused relu/w2/mask/score epilogue
// GEMM structure: BM=BN=256, BK=64, 8 waves (2Mx4N), wave-tile 128x64
// (M_rep=8,N_rep=4), LDS 2x(32+32)KB dbuf, per-K-tile 4 phases:
// {stage 2 gload_lds ; ds_read quadrant ; s_barrier ; setprio1 16xMFMA setprio0},
// boundary __syncthreads per K-tile. T2 swizzle via pre-swizzled global source.
// Workspace: 125,067,264 bytes.

typedef unsigned short u16;
typedef unsigned int u32;
typedef __attribute__((ext_vector_type(8))) short bf16x8;
typedef __attribute__((ext_vector_type(4))) float f32x4;

#define NUM_TABLES 10
#define MPAD 6144
#define DD 768

__device__ __forceinline__ u16 f2bf(float f) {
  u32 u = __builtin_bit_cast(u32, f);
  u32 r = u + 0x7FFFu + ((u >> 16) & 1u);
  return (u16)(r >> 16);
}
__device__ __forceinline__ float bf2f(u16 h) {
  u32 u = ((u32)h) << 16;
  return __builtin_bit_cast(float, u);
}

__device__ __forceinline__ void gload_lds16(const u16* g, u16* l) {
  __builtin_amdgcn_global_load_lds(
      (const __attribute__((address_space(1))) void*)g,
      (__attribute__((address_space(3))) void*)l, 16, 0, 0);
}

// ---------------- fused prep (one dispatch) ----------------
__global__ void prep_all(const float* __restrict__ qps, uint4* __restrict__ qpad,
                         const float* __restrict__ Ans, const float* __restrict__ Wp,
                         const float* __restrict__ Wt, u16* __restrict__ Bcat,
                         const float* __restrict__ Wf1, uint4* __restrict__ Wf1b,
                         const float* __restrict__ bp, const float* __restrict__ bt,
                         float* __restrict__ cp, float* __restrict__ ct,
                         const float* __restrict__ mask, const float* __restrict__ bf2,
                         float* __restrict__ out) {
  int blk = blockIdx.x;
  int tid = threadIdx.x;
  if (blk < 9216) {
    // ---- Qpad: cast l=1 slice to bf16, pad rows [6000,6144) ----
    size_t c = (size_t)blk * 256 + tid;
    const int per_b = MPAD * (DD / 8);
    if (c >= (size_t)4 * per_b) return;
    int b = (int)(c / per_b);
    int rr = (int)(c % per_b);
    int r = rr / (DD / 8);
    int kc = rr % (DD / 8);
    uint4 o;
    if (r < 6000) {
      const float* src = qps + (((size_t)(b * 2 + 1)) * 6000 + r) * DD + kc * 8;
      float4 f0 = *(const float4*)src;
      float4 f1 = *(const float4*)(src + 4);
      o.x = (u32)f2bf(f0.x) | ((u32)f2bf(f0.y) << 16);
      o.y = (u32)f2bf(f0.z) | ((u32)f2bf(f0.w) << 16);
      o.z = (u32)f2bf(f1.x) | ((u32)f2bf(f1.y) << 16);
      o.w = (u32)f2bf(f1.z) | ((u32)f2bf(f1.w) << 16);
    } else {
      o = make_uint4(0, 0, 0, 0);
    }
    qpad[c] = o;
  } else if (blk < 11520) {
    // ---- Bcat = [Wp2 + A*Wp3 ; Wt2 + A*Wt3] ----
    size_t c = (size_t)(blk - 9216) * 256 + tid;
    const int per_b = DD * (DD / 4);
    if (c >= (size_t)4 * per_b) return;
    int b = (int)(c / per_b);
    int rr = (int)(c % per_b);
    int d = rr / (DD / 4);
    int k4 = (rr % (DD / 4)) * 4;
    float4 av = *(const float4*)(Ans + ((size_t)b * 2 + 1) * DD + k4);
    float4 p2 = *(const float4*)(Wp + (size_t)d * 2304 + 768 + k4);
    float4 p3 = *(const float4*)(Wp + (size_t)d * 2304 + 1536 + k4);
    float4 t2 = *(const float4*)(Wt + (size_t)d * 2304 + 768 + k4);
    float4 t3 = *(const float4*)(Wt + (size_t)d * 2304 + 1536 + k4);
    uint2 op, ot;
    op.x = (u32)f2bf(p2.x + av.x * p3.x) | ((u32)f2bf(p2.y + av.y * p3.y) << 16);
    op.y = (u32)f2bf(p2.z + av.z * p3.z) | ((u32)f2bf(p2.w + av.w * p3.w) << 16);
    ot.x = (u32)f2bf(t2.x + av.x * t3.x) | ((u32)f2bf(t2.y + av.y * t3.y) << 16);
    ot.y = (u32)f2bf(t2.z + av.z * t3.z) | ((u32)f2bf(t2.w + av.w * t3.w) << 16);
    size_t ip = ((size_t)b * 1536 + d) * DD + k4;
    size_t it = ((size_t)b * 1536 + 768 + d) * DD + k4;
    *(uint2*)(Bcat + ip) = op;
    *(uint2*)(Bcat + it) = ot;
  } else if (blk < 12096) {
    // ---- Wf1 cast ----
    size_t c = (size_t)(blk - 11520) * 256 + tid;
    if (c >= (size_t)DD * 1536 / 8) return;
    const float* src = Wf1 + c * 8;
    float4 f0 = *(const float4*)src;
    float4 f1 = *(const float4*)(src + 4);
    uint4 o;
    o.x = (u32)f2bf(f0.x) | ((u32)f2bf(f0.y) << 16);
    o.y = (u32)f2bf(f0.z) | ((u32)f2bf(f0.w) << 16);
    o.z = (u32)f2bf(f1.x) | ((u32)f2bf(f1.y) << 16);
    o.w = (u32)f2bf(f1.z) | ((u32)f2bf(f1.w) << 16);
    Wf1b[c] = o;
  } else if (blk < 13632) {
    // ---- cp/ct parallel: one block per (matrix, d) ----
    int e = blk - 12096;          // 0..1535
    int isT = e >= 768;
    int d = e - (isT ? 768 : 0);
    const float* wrow = (isT ? Wt : Wp) + (size_t)d * 2304;
    float a0 = 0.f, a1 = 0.f, a2 = 0.f, a3 = 0.f;
    for (int k = tid; k < DD; k += 256) {
      float w = wrow[k];
      a0 += w * Ans[1 * DD + k];
      a1 += w * Ans[3 * DD + k];
      a2 += w * Ans[5 * DD + k];
      a3 += w * Ans[7 * DD + k];
    }
#pragma unroll
    for (int off = 32; off > 0; off >>= 1) {
      a0 += __shfl_down(a0, off);
      a1 += __shfl_down(a1, off);
      a2 += __shfl_down(a2, off);
      a3 += __shfl_down(a3, off);
    }
    __shared__ float red[4][4];
    int wid = tid >> 6;
    if ((tid & 63) == 0) {
      red[wid][0] = a0; red[wid][1] = a1; red[wid][2] = a2; red[wid][3] = a3;
    }
    __syncthreads();
    if (tid < 4) {
      float s = red[0][tid] + red[1][tid] + red[2][tid] + red[3][tid];
      float bias = (isT ? bt : bp)[d];
      (isT ? ct : cp)[tid * DD + d] = s + bias;
    }
  } else {
    // ---- out init = bf2 * msum ----
    int idx = (blk - 13632) * 256 + tid;
    if (idx >= 400) return;
    const float* m = mask + (size_t)idx * 60;
    float s = 0.f;
    for (int t = 0; t < 60; ++t) s += m[t];
    out[idx] = bf2[0] * s;
  }
}

// ---------------- gemm12: [ps|ts] = Qpad @ Bcat^T + [cp|ct] ----------------
// 256x256 tile, BK=64, 8 waves (2Mx4N), wave-tile 128x64. Grid 576 XCD-chunked.
__global__ __launch_bounds__(512, 2)
void gemm12(const u16* __restrict__ Q, const u16* __restrict__ Bcat,
            const float* __restrict__ cp, const float* __restrict__ ct,
            u16* __restrict__ ps, u16* __restrict__ ts) {
  int flat = blockIdx.x;
  int lid = (flat & 7) * 72 + (flat >> 3);
  int n = lid % 6;
  int m = (lid / 6) % 24;
  int b = lid / 144;

  const int m0 = m * 256;
  const int n0 = n * 256;
  const int tid = threadIdx.x;
  const int lane = tid & 63;
  const int wid = tid >> 6;     // 0..7
  const int wm = wid >> 2;      // 0..1
  const int wn = wid & 3;       // 0..3

  __shared__ u16 As[2][256 * 64];
  __shared__ u16 Bs[2][256 * 64];

  const u16* Abase = Q + (size_t)b * MPAD * DD;
  const u16* Bbase = Bcat + (size_t)b * 1536 * DD;

  f32x4 acc[8][4] = {};

  const int lrow = tid >> 3;                       // 0..63
  const int lcol_s = (((tid & 7) ^ (lrow & 7)) * 8);  // pre-swizzled src col
  const int axor = (lane & 7) << 3;                // read-side XOR

  const u16* aptr[4];
  const u16* bptr[4];
#pragma unroll
  for (int j = 0; j < 4; ++j) {
    aptr[j] = Abase + (size_t)(m0 + lrow + j * 64) * DD + lcol_s;
    bptr[j] = Bbase + (size_t)(n0 + lrow + j * 64) * DD + lcol_s;
  }
  const int dbase = wid * 8;  // wave-uniform LDS row base

  // prologue: stage K-tile 0 into buf 0
#pragma unroll
  for (int j = 0; j < 4; ++j) {
    gload_lds16(aptr[j], &As[0][(dbase + j * 64) * 64]);
    gload_lds16(bptr[j], &Bs[0][(dbase + j * 64) * 64]);
    aptr[j] += 64; bptr[j] += 64;
  }
  __syncthreads();

  int cur = 0;
  for (int t = 0; t < 12; ++t) {
    const bool pf = (t < 11);
    bf16x8 af[2][4], bfr[2][4];
    // ---- phase 0: stage A(0,1); read A-half0 + B-half0; MFMA q(0,0) ----
    if (pf) {
      gload_lds16(aptr[0], &As[cur ^ 1][(dbase + 0 * 64) * 64]);
      gload_lds16(aptr[1], &As[cur ^ 1][(dbase + 1 * 64) * 64]);
    }
#pragma unroll
    for (int kf = 0; kf < 2; ++kf)
#pragma unroll
      for (int mf = 0; mf < 4; ++mf)
        af[kf][mf] = *(const bf16x8*)&As[cur][(wm * 128 + mf * 16 + (lane & 15)) * 64 + ((kf * 32 + (lane >> 4) * 8) ^ axor)];
#pragma unroll
    for (int kf = 0; kf < 2; ++kf)
#pragma unroll
      for (int nf = 0; nf < 2; ++nf)
        bfr[kf][nf] = *(const bf16x8*)&Bs[cur][(wn * 64 + nf * 16 + (lane & 15)) * 64 + ((kf * 32 + (lane >> 4) * 8) ^ axor)];
    __builtin_amdgcn_s_barrier();
    __builtin_amdgcn_s_setprio(1);
#pragma unroll
    for (int mf = 0; mf < 4; ++mf)
#pragma unroll
      for (int nf = 0; nf < 2; ++nf) {
        acc[mf][nf] = __builtin_amdgcn_mfma_f32_16x16x32_bf16(af[0][mf], bfr[0][nf], acc[mf][nf], 0, 0, 0);
        acc[mf][nf] = __builtin_amdgcn_mfma_f32_16x16x32_bf16(af[1][mf], bfr[1][nf], acc[mf][nf], 0, 0, 0);
      }
    __builtin_amdgcn_s_setprio(0);
    // ---- phase 1: stage A(2,3); read B-half1; MFMA q(0,1) ----
    if (pf) {
      gload_lds16(aptr[2], &As[cur ^ 1][(dbase + 2 * 64) * 64]);
      gload_lds16(aptr[3], &As[cur ^ 1][(dbase + 3 * 64) * 64]);
#pragma unroll
      for (int j = 0; j < 4; ++j) aptr[j] += 64;
    }
#pragma unroll
    for (int kf = 0; kf < 2; ++kf)
#pragma unroll
      for (int nf = 2; nf < 4; ++nf)
        bfr[kf][nf] = *(const bf16x8*)&Bs[cur][(wn * 64 + nf * 16 + (lane & 15)) * 64 + ((kf * 32 + (lane >> 4) * 8) ^ axor)];
    __builtin_amdgcn_s_barrier();
    __builtin_amdgcn_s_setprio(1);
#pragma unroll
    for (int mf = 0; mf < 4; ++mf)
#pragma unroll
      for (int nf = 2; nf < 4; ++nf) {
        acc[mf][nf] = __builtin_amdgcn_mfma_f32_16x16x32_bf16(af[0][mf], bfr[0][nf], acc[mf][nf], 0, 0, 0);
        acc[mf][nf] = __builtin_amdgcn_mfma_f32_16x16x32_bf16(af[1][mf], bfr[1][nf], acc[mf][nf], 0, 0, 0);
      }
    __builtin_amdgcn_s_setprio(0);
    // ---- phase 2: stage B(0,1); read A-half1; MFMA q(1,0) ----
    if (pf) {
      gload_lds16(bptr[0], &Bs[cur ^ 1][(dbase + 0 * 64) * 64]);
      gload_lds16(bptr[1], &Bs[cur ^ 1][(dbase + 1 * 64) * 64]);
    }
#pragma unroll
    for (int kf = 0; kf < 2; ++kf)
#pragma unroll
      for (int mf = 0; mf < 4; ++mf)
        af[kf][mf] = *(const bf16x8*)&As[cur][(wm * 128 + (mf + 4) * 16 + (lane & 15)) * 64 + ((kf * 32 + (lane >> 4) * 8) ^ axor)];
    __builtin_amdgcn_s_barrier();
    __builtin_amdgcn_s_setprio(1);
#pragma unroll
    for (int mf = 0; mf < 4; ++mf)
#pragma unroll
      for (int nf = 0; nf < 2; ++nf) {
        acc[mf + 4][nf] = __builtin_amdgcn_mfma_f32_16x16x32_bf16(af[0][mf], bfr[0][nf], acc[mf + 4][nf], 0, 0, 0);
        acc[mf + 4][nf] = __builtin_amdgcn_mfma_f32_16x16x32_bf16(af[1][mf], bfr[1][nf], acc[mf + 4][nf], 0, 0, 0);
      }
    __builtin_amdgcn_s_setprio(0);
    // ---- phase 3: stage B(2,3); MFMA q(1,1) ----
    if (pf) {
      gload_lds16(bptr[2], &Bs[cur ^ 1][(dbase + 2 * 64) * 64]);
      gload_lds16(bptr[3], &Bs[cur ^ 1][(dbase + 3 * 64) * 64]);
#pragma unroll
      for (int j = 0; j < 4; ++j) bptr[j] += 64;
    }
    __builtin_amdgcn_s_barrier();
    __builtin_amdgcn_s_setprio(1);
#pragma unroll
    for (int mf = 0; mf < 4; ++mf)
#pragma unroll
      for (int nf = 2; nf < 4; ++nf) {
        acc[mf + 4][nf] = __builtin_amdgcn_mfma_f32_16x16x32_bf16(af[0][mf], bfr[0][nf], acc[mf + 4][nf], 0, 0, 0);
        acc[mf + 4][nf] = __builtin_amdgcn_mfma_f32_16x16x32_bf16(af[1][mf], bfr[1][nf], acc[mf + 4][nf], 0, 0, 0);
      }
    __builtin_amdgcn_s_setprio(0);
    __syncthreads();   // boundary: drains stage(t+1), flips buffers
    cur ^= 1;
  }

  u16* dst = (n0 < 768 ? ps : ts) + (size_t)b * MPAD * DD;
  const float* cv = (n0 < 768 ? cp : ct) + b * DD;
  const int ncol0 = n0 - (n0 < 768 ? 0 : 768);
#pragma unroll
  for (int mf = 0; mf < 8; ++mf)
#pragma unroll
    for (int nf = 0; nf < 4; ++nf)
#pragma unroll
      for (int r = 0; r < 4; ++r) {
        int row = m0 + wm * 128 + mf * 16 + (lane >> 4) * 4 + r;
        int col = ncol0 + wn * 64 + nf * 16 + (lane & 15);
        dst[(size_t)row * DD + col] = f2bf(acc[mf][nf][r] + cv[col]);
      }
}

// ---------------- table max ----------------
__global__ void table_max_kernel(const u16* __restrict__ ts, const int* __restrict__ ids,
                                 u16* __restrict__ tmax) {
  int bi = blockIdx.x;  // 4*60*3 = 720
  int b = bi / 180;
  int rem = bi % 180;
  int tok = rem / 3;
  int dc = rem % 3;
  int d = dc * 256 + threadIdx.x;
  __shared__ int sids[100];
  if (threadIdx.x < 100) sids[threadIdx.x] = ids[b * 100 + threadIdx.x];
  __syncthreads();
  float m[NUM_TABLES];
#pragma unroll
  for (int t = 0; t < NUM_TABLES; ++t) m[t] = -INFINITY;
  const u16* base = ts + ((size_t)b * MPAD + tok) * DD + d;
  for (int p = 0; p < 100; ++p) {
    float v = bf2f(base[(size_t)p * 60 * DD]);
    int id = sids[p];
#pragma unroll
    for (int t = 0; t < NUM_TABLES; ++t)
      if (id == t) m[t] = fmaxf(m[t], v);
  }
#pragma unroll
  for (int t = 0; t < NUM_TABLES; ++t)
    tmax[(((size_t)b * NUM_TABLES + t) * 60 + tok) * DD + d] = f2bf(m[t]);
}

// ---------------- gemm3 + fused score ----------------
__global__ __launch_bounds__(512, 2)
void gemm3s(const u16* __restrict__ ps, const u16* __restrict__ tmax,
            const int* __restrict__ ids, const u16* __restrict__ Wf1b,
            const float* __restrict__ bf1, const float* __restrict__ w2,
            const float* __restrict__ mask, float* __restrict__ out) {
  int flat = blockIdx.x;
  int lid = (flat & 7) * 36 + (flat >> 3);
  int n = lid % 3;
  int m = (lid / 3) % 24;
  int b = lid / 72;

  const int m0 = m * 256;
  const int n0 = n * 256;
  const int tid = threadIdx.x;
  const int lane = tid & 63;
  const int wid = tid >> 6;
  const int wm = wid >> 2;
  const int wn = wid & 3;

  __shared__ u16 As[2][256 * 64];
  __shared__ u16 Bs[2][256 * 64];
  __shared__ int sids[100];
  __shared__ float pacc[6];
  if (tid < 100) sids[tid] = ids[b * 100 + tid];
  if (tid < 6) pacc[tid] = 0.f;
  __syncthreads();

  const u16* Abase = ps + (size_t)b * MPAD * DD;
  const u16* Tbase = tmax + (size_t)b * NUM_TABLES * 60 * DD;

  f32x4 acc[8][4] = {};

  const int lrow = tid >> 3;
  const int lcol_s = (((tid & 7) ^ (lrow & 7)) * 8);
  const int axor = (lane & 7) << 3;

  const u16* aptr[4];
  const u16* tptr[4];
  const u16* bptr[4];
#pragma unroll
  for (int j = 0; j < 4; ++j) {
    int row = m0 + lrow + j * 64;
    aptr[j] = Abase + (size_t)row * DD + lcol_s;
    int rp = row < 6000 ? row : 5999;
    int p = (unsigned)rp / 60u;
    int tok = rp - p * 60;
    int id = sids[p];
    tptr[j] = Tbase + ((size_t)(id * 60 + tok)) * DD + lcol_s;
    bptr[j] = Wf1b + (size_t)(n0 + lrow + j * 64) * 1536 + lcol_s;
  }
  const int dbase = wid * 8;

  // prologue: stage K-tile 0 into buf 0 (from ps)
#pragma unroll
  for (int j = 0; j < 4; ++j) {
    gload_lds16(aptr[j], &As[0][(dbase + j * 64) * 64]);
    gload_lds16(bptr[j], &Bs[0][(dbase + j * 64) * 64]);
    aptr[j] += 64; bptr[j] += 64;
  }
  __syncthreads();

  int cur = 0;
  for (int t = 0; t < 24; ++t) {
    const bool pf = (t < 23);
    if (t + 1 == 12) {
#pragma unroll
      for (int j = 0; j < 4; ++j) aptr[j] = tptr[j];  // switch A source to tmax gather
    }
    bf16x8 af[2][4], bfr[2][4];
    // ---- phase 0 ----
    if (pf) {
      gload_lds16(aptr[0], &As[cur ^ 1][(dbase + 0 * 64) * 64]);
      gload_lds16(aptr[1], &As[cur ^ 1][(dbase + 1 * 64) * 64]);
    }
#pragma unroll
    for (int kf = 0; kf < 2; ++kf)
#pragma unroll
      for (int mf = 0; mf < 4; ++mf)
        af[kf][mf] = *(const bf16x8*)&As[cur][(wm * 128 + mf * 16 + (lane & 15)) * 64 + ((kf * 32 + (lane >> 4) * 8) ^ axor)];
#pragma unroll
    for (int kf = 0; kf < 2; ++kf)
#pragma unroll
      for (int nf = 0; nf < 2; ++nf)
        bfr[kf][nf] = *(const bf16x8*)&Bs[cur][(wn * 64 + nf * 16 + (lane & 15)) * 64 + ((kf * 32 + (lane >> 4) * 8) ^ axor)];
    __builtin_amdgcn_s_barrier();
    __builtin_amdgcn_s_setprio(1);
#pragma unroll
    for (int mf = 0; mf < 4; ++mf)
#pragma unroll
      for (int nf = 0; nf < 2; ++nf) {
        acc[mf][nf] = __builtin_amdgcn_mfma_f32_16x16x32_bf16(af[0][mf], bfr[0][nf], acc[mf][nf], 0, 0, 0);
        acc[mf][nf] = __builtin_amdgcn_mfma_f32_16x16x32_bf16(af[1][mf], bfr[1][nf], acc[mf][nf], 0, 0, 0);
      }
    __builtin_amdgcn_s_setprio(0);
    // ---- phase 1 ----
    if (pf) {
      gload_lds16(aptr[2], &As[cur ^ 1][(dbase + 2 * 64) * 64]);
      gload_lds16(aptr[3], &As[cur ^ 1][(dbase + 3 * 64) * 64]);
#pragma unroll
      for (int j = 0; j < 4; ++j) aptr[j] += 64;
    }
#pragma unroll
    for (int kf = 0; kf < 2; ++kf)
#pragma unroll
      for (int nf = 2; nf < 4; ++nf)
        bfr[kf][nf] = *(const bf16x8*)&Bs[cur][(wn * 64 + nf * 16 + (lane & 15)) * 64 + ((kf * 32 + (lane >> 4) * 8) ^ axor)];
    __builtin_amdgcn_s_barrier();
    __builtin_amdgcn_s_setprio(1);
#pragma unroll
    for (int mf = 0; mf < 4; ++mf)
#pragma unroll
      for (int nf = 2; nf < 4; ++nf) {
        acc[mf][nf] = __builtin_amdgcn_mfma_f32_16x16x32_bf16(af[0][mf], bfr[0][nf], acc[mf][nf], 0, 0, 0);
        acc[mf][nf] = __builtin_amdgcn_mfma_f32_16x16x32_bf16(af[1][mf], bfr[1][nf], acc[mf][nf], 0, 0, 0);
      }
    __builtin_amdgcn_s_setprio(0);
    // ---- phase 2 ----
    if (pf) {
      gload_lds16(bptr[0], &Bs[cur ^ 1][(dbase + 0 * 64) * 64]);
      gload_lds16(bptr[1], &Bs[cur ^ 1][(dbase + 1 * 64) * 64]);
    }
#pragma unroll
    for (int kf = 0; kf < 2; ++kf)
#pragma unroll
      for (int mf = 0; mf < 4; ++mf)
        af[kf][mf] = *(const bf16x8*)&As[cur][(wm * 128 + (mf + 4) * 16 + (lane & 15)) * 64 + ((kf * 32 + (lane >> 4) * 8) ^ axor)];
    __builtin_amdgcn_s_barrier();
    __builtin_amdgcn_s_setprio(1);
#pragma unroll
    for (int mf = 0; mf < 4; ++mf)
#pragma unroll
      for (int nf = 0; nf < 2; ++nf) {
        acc[mf + 4][nf] = __builtin_amdgcn_mfma_f32_16x16x32_bf16(af[0][mf], bfr[0][nf], acc[mf + 4][nf], 0, 0, 0);
        acc[mf + 4][nf] = __builtin_amdgcn_mfma_f32_16x16x32_bf16(af[1][mf], bfr[1][nf], acc[mf + 4][nf], 0, 0, 0);
      }
    __builtin_amdgcn_s_setprio(0);
    // ---- phase 3 ----
    if (pf) {
      gload_lds16(bptr[2], &Bs[cur ^ 1][(dbase + 2 * 64) * 64]);
      gload_lds16(bptr[3], &Bs[cur ^ 1][(dbase + 3 * 64) * 64]);
#pragma unroll
      for (int j = 0; j < 4; ++j) bptr[j] += 64;
    }
    __builtin_amdgcn_s_barrier();
    __builtin_amdgcn_s_setprio(1);
#pragma unroll
    for (int mf = 0; mf < 4; ++mf)
#pragma unroll
      for (int nf = 2; nf < 4; ++nf) {
        acc[mf + 4][nf] = __builtin_amdgcn_mfma_f32_16x16x32_bf16(af[0][mf], bfr[0][nf], acc[mf + 4][nf], 0, 0, 0);
        acc[mf + 4][nf] = __builtin_amdgcn_mfma_f32_16x16x32_bf16(af[1][mf], bfr[1][nf], acc[mf + 4][nf], 0, 0, 0);
      }
    __builtin_amdgcn_s_setprio(0);
    __syncthreads();
    cur ^= 1;
  }

  // fused score epilogue
  float b1v[4], w2v[4];
#pragma unroll
  for (int nf = 0; nf < 4; ++nf) {
    int c = n0 + wn * 64 + nf * 16 + (lane & 15);
    b1v[nf] = bf1[c];
    w2v[nf] = w2[c];
  }
  const int pfirst = m0 / 60;
#pragma unroll
  for (int mf = 0; mf < 8; ++mf)
#pragma unroll
    for (int r = 0; r < 4; ++r) {
      int row = m0 + wm * 128 + mf * 16 + (lane >> 4) * 4 + r;
      float s = 0.f;
#pragma unroll
      for (int nf = 0; nf < 4; ++nf)
        s += fmaxf(acc[mf][nf][r] + b1v[nf], 0.f) * w2v[nf];
      s += __shfl_xor(s, 1);
      s += __shfl_xor(s, 2);
      s += __shfl_xor(s, 4);
      s += __shfl_xor(s, 8);
      if ((lane & 15) == 0 && row < 6000) {
        int p = (unsigned)row / 60u;
        int tok = row - p * 60;
        float mk = mask[((size_t)b * 100 + p) * 60 + tok];
        atomicAdd(&pacc[p - pfirst], mk * s);
      }
    }
  __syncthreads();
  int plast = (m0 + 255 < 6000 ? m0 + 255 : 5999) / 60;
  if (tid <= plast - pfirst)
    atomicAdd(out + b * 100 + pfirst + tid, pacc[tid]);
}

// ---------------- launch ----------------
extern "C" void kernel_launch(void* const* d_in, const int* in_sizes, int n_in,
                              void* d_out, int out_size, void* d_ws, size_t ws_size,
                              hipStream_t stream) {
  const float* answer = (const float*)d_in[0];
  const float* qps    = (const float*)d_in[1];
  const float* mask   = (const float*)d_in[2];
  const int*   tids   = (const int*)d_in[3];
  const float* Wp     = (const float*)d_in[4];
  const float* bp     = (const float*)d_in[5];
  const float* Wt     = (const float*)d_in[6];
  const float* bt     = (const float*)d_in[7];
  const float* Wf1    = (const float*)d_in[8];
  const float* bf1    = (const float*)d_in[9];
  const float* Wf2    = (const float*)d_in[10];
  const float* bf2    = (const float*)d_in[11];
  float* out = (float*)d_out;

  char* ws = (char*)d_ws;
  // region layout (bytes); total 125,067,264. tmax aliases Qpad (dead after gemm12).
  u16* Qpad = (u16*)(ws + 0);             // 37,748,736 (4x6144x768x2)
  u16* ps   = (u16*)(ws + 37748736);      // 37,748,736
  u16* ts   = (u16*)(ws + 75497472);      // 37,748,736
  u16* Bcat = (u16*)(ws + 113246208);     // 9,437,184
  u16* Wf1b = (u16*)(ws + 122683392);     // 2,359,296
  float* cp = (float*)(ws + 125042688);   // 12,288
  float* ct = (float*)(ws + 125054976);   // 12,288
  u16* tmax = (u16*)(ws + 0);             // 3,686,400 (aliases Qpad)

  prep_all<<<13634, 256, 0, stream>>>(qps, (uint4*)Qpad, answer, Wp, Wt, Bcat,
                                      Wf1, (uint4*)Wf1b, bp, bt, cp, ct,
                                      mask, bf2, out);

  gemm12<<<576, 512, 0, stream>>>(Qpad, Bcat, cp, ct, ps, ts);

  table_max_kernel<<<720, 256, 0, stream>>>(ts, tids, tmax);

  gemm3s<<<288, 512, 0, stream>>>(ps, tmax, tids, Wf1b, bf1, Wf2, mask, out);
}

// Round 7
// 226.949 us; speedup vs baseline: 1.2564x; 1.2564x over previous
//
#include <hip/hip_runtime.h>
#include <hip/hip_bf16.h>

// FusionRetrModel: B=4, NL=2 (only l=1 used), P=100, TOK=60, T=6000, D=768.
// R7 pipeline (Ht factorization):
//   prep_all: Qpad bf16 [4][6016][768]; Bcat=[Wpb;Wtb]; Wf1 bf16; cp/ct; out init.
//   gemm12: [ps|ts] = Qpad @ Bcat^T + [cp|ct]       (128^2 dbuf 2-phase, swizzled)
//   tmax:   tmax[b][t][tok][:] = max over p with ids==t of ts   (600 rows/batch)
//   gemm_t: Ht = tmax @ Wf1_hi^T  (f32 out, M=640 pad, K=768 — only 2.9 GF: the
//           gather half of H has just 600 distinct rows, not 6000)
//   gemm_h: Hp = ps @ Wf1_lo^T (K=768); epilogue H = Hp + Ht[gather] + bf1,
//           relu, dot w2, mask-weighted per-passage reduce -> atomicAdd out.
// tmax/Ht alias the dead Qpad region. Workspace: 126,394,368 bytes.

typedef unsigned short u16;
typedef unsigned int u32;
typedef __attribute__((ext_vector_type(8))) short bf16x8;
typedef __attribute__((ext_vector_type(4))) float f32x4;

#define NUM_TABLES 10
#define MPAD 6016
#define DD 768

__device__ __forceinline__ u16 f2bf(float f) {
  u32 u = __builtin_bit_cast(u32, f);
  u32 r = u + 0x7FFFu + ((u >> 16) & 1u);
  return (u16)(r >> 16);
}
__device__ __forceinline__ float bf2f(u16 h) {
  u32 u = ((u32)h) << 16;
  return __builtin_bit_cast(float, u);
}

__device__ __forceinline__ void gload_lds16(const u16* g, u16* l) {
  __builtin_amdgcn_global_load_lds(
      (const __attribute__((address_space(1))) void*)g,
      (__attribute__((address_space(3))) void*)l, 16, 0, 0);
}

// ---------------- fused prep (one dispatch) ----------------
__global__ void prep_all(const float* __restrict__ qps, uint4* __restrict__ qpad,
                         const float* __restrict__ Ans, const float* __restrict__ Wp,
                         const float* __restrict__ Wt, u16* __restrict__ Bcat,
                         const float* __restrict__ Wf1, uint4* __restrict__ Wf1b,
                         const float* __restrict__ bp, const float* __restrict__ bt,
                         float* __restrict__ cp, float* __restrict__ ct,
                         const float* __restrict__ mask, const float* __restrict__ bf2,
                         float* __restrict__ out) {
  int blk = blockIdx.x;
  int tid = threadIdx.x;
  if (blk < 9024) {
    // ---- Qpad: cast l=1 slice to bf16, pad rows [6000,6016) ----
    size_t c = (size_t)blk * 256 + tid;
    const int per_b = MPAD * (DD / 8);
    if (c >= (size_t)4 * per_b) return;
    int b = (int)(c / per_b);
    int rr = (int)(c % per_b);
    int r = rr / (DD / 8);
    int kc = rr % (DD / 8);
    uint4 o;
    if (r < 6000) {
      const float* src = qps + (((size_t)(b * 2 + 1)) * 6000 + r) * DD + kc * 8;
      float4 f0 = *(const float4*)src;
      float4 f1 = *(const float4*)(src + 4);
      o.x = (u32)f2bf(f0.x) | ((u32)f2bf(f0.y) << 16);
      o.y = (u32)f2bf(f0.z) | ((u32)f2bf(f0.w) << 16);
      o.z = (u32)f2bf(f1.x) | ((u32)f2bf(f1.y) << 16);
      o.w = (u32)f2bf(f1.z) | ((u32)f2bf(f1.w) << 16);
    } else {
      o = make_uint4(0, 0, 0, 0);
    }
    qpad[c] = o;
  } else if (blk < 11328) {
    // ---- Bcat = [Wp2 + A*Wp3 ; Wt2 + A*Wt3] ----
    size_t c = (size_t)(blk - 9024) * 256 + tid;
    const int per_b = DD * (DD / 4);
    if (c >= (size_t)4 * per_b) return;
    int b = (int)(c / per_b);
    int rr = (int)(c % per_b);
    int d = rr / (DD / 4);
    int k4 = (rr % (DD / 4)) * 4;
    float4 av = *(const float4*)(Ans + ((size_t)b * 2 + 1) * DD + k4);
    float4 p2 = *(const float4*)(Wp + (size_t)d * 2304 + 768 + k4);
    float4 p3 = *(const float4*)(Wp + (size_t)d * 2304 + 1536 + k4);
    float4 t2 = *(const float4*)(Wt + (size_t)d * 2304 + 768 + k4);
    float4 t3 = *(const float4*)(Wt + (size_t)d * 2304 + 1536 + k4);
    uint2 op, ot;
    op.x = (u32)f2bf(p2.x + av.x * p3.x) | ((u32)f2bf(p2.y + av.y * p3.y) << 16);
    op.y = (u32)f2bf(p2.z + av.z * p3.z) | ((u32)f2bf(p2.w + av.w * p3.w) << 16);
    ot.x = (u32)f2bf(t2.x + av.x * t3.x) | ((u32)f2bf(t2.y + av.y * t3.y) << 16);
    ot.y = (u32)f2bf(t2.z + av.z * t3.z) | ((u32)f2bf(t2.w + av.w * t3.w) << 16);
    size_t ip = ((size_t)b * 1536 + d) * DD + k4;
    size_t it = ((size_t)b * 1536 + 768 + d) * DD + k4;
    *(uint2*)(Bcat + ip) = op;
    *(uint2*)(Bcat + it) = ot;
  } else if (blk < 11904) {
    // ---- Wf1 cast ----
    size_t c = (size_t)(blk - 11328) * 256 + tid;
    if (c >= (size_t)DD * 1536 / 8) return;
    const float* src = Wf1 + c * 8;
    float4 f0 = *(const float4*)src;
    float4 f1 = *(const float4*)(src + 4);
    uint4 o;
    o.x = (u32)f2bf(f0.x) | ((u32)f2bf(f0.y) << 16);
    o.y = (u32)f2bf(f0.z) | ((u32)f2bf(f0.w) << 16);
    o.z = (u32)f2bf(f1.x) | ((u32)f2bf(f1.y) << 16);
    o.w = (u32)f2bf(f1.z) | ((u32)f2bf(f1.w) << 16);
    Wf1b[c] = o;
  } else if (blk < 13440) {
    // ---- cp/ct parallel: one block per (matrix, d) ----
    int e = blk - 11904;          // 0..1535
    int isT = e >= 768;
    int d = e - (isT ? 768 : 0);
    const float* wrow = (isT ? Wt : Wp) + (size_t)d * 2304;
    float a0 = 0.f, a1 = 0.f, a2 = 0.f, a3 = 0.f;
    for (int k = tid; k < DD; k += 256) {
      float w = wrow[k];
      a0 += w * Ans[1 * DD + k];
      a1 += w * Ans[3 * DD + k];
      a2 += w * Ans[5 * DD + k];
      a3 += w * Ans[7 * DD + k];
    }
#pragma unroll
    for (int off = 32; off > 0; off >>= 1) {
      a0 += __shfl_down(a0, off);
      a1 += __shfl_down(a1, off);
      a2 += __shfl_down(a2, off);
      a3 += __shfl_down(a3, off);
    }
    __shared__ float red[4][4];
    int wid = tid >> 6;
    if ((tid & 63) == 0) {
      red[wid][0] = a0; red[wid][1] = a1; red[wid][2] = a2; red[wid][3] = a3;
    }
    __syncthreads();
    if (tid < 4) {
      float s = red[0][tid] + red[1][tid] + red[2][tid] + red[3][tid];
      float bias = (isT ? bt : bp)[d];
      (isT ? ct : cp)[tid * DD + d] = s + bias;
    }
  } else {
    // ---- out init = bf2 * msum ----
    int idx = (blk - 13440) * 256 + tid;
    if (idx >= 400) return;
    const float* m = mask + (size_t)idx * 60;
    float s = 0.f;
    for (int t = 0; t < 60; ++t) s += m[t];
    out[idx] = bf2[0] * s;
  }
}

// ---------------- gemm12: [ps|ts] = Qpad @ Bcat^T + [cp|ct] ----------------
// dbuf 2-phase + swizzle. Grid 2256 flat, XCD-chunked, n-fastest.
__global__ __launch_bounds__(256, 2)
void gemm12(const u16* __restrict__ Q, const u16* __restrict__ Bcat,
            const float* __restrict__ cp, const float* __restrict__ ct,
            u16* __restrict__ ps, u16* __restrict__ ts) {
  int flat = blockIdx.x;
  int lid = (flat & 7) * 282 + (flat >> 3);
  int n = lid % 12;
  int m = (lid / 12) % 47;
  int b = lid / 564;

  const int m0 = m * 128;
  const int n0 = n * 128;
  const int tid = threadIdx.x;
  const int lane = tid & 63;
  const int wid = tid >> 6;
  const int wm = wid >> 1, wn = wid & 1;

  __shared__ u16 As[2][128 * 64];
  __shared__ u16 Bs[2][128 * 64];

  const u16* Abase = Q + (size_t)b * MPAD * DD;
  const u16* Bbase = Bcat + (size_t)b * 1536 * DD;

  f32x4 acc[4][4] = {};

  const int lrow = lane >> 3;
  const int lcol_s = (((lane & 7) ^ (lrow & 7)) * 8);  // pre-swizzled src col
  const int axor = (lane & 7) << 3;                    // read-side XOR

  const u16* aptr[4];
  const u16* bptr[4];
#pragma unroll
  for (int j = 0; j < 4; ++j) {
    aptr[j] = Abase + (size_t)(m0 + wid * 32 + j * 8 + lrow) * DD + lcol_s;
    bptr[j] = Bbase + (size_t)(n0 + wid * 32 + j * 8 + lrow) * DD + lcol_s;
  }

  // prologue: stage kt=0 into buf 0
#pragma unroll
  for (int j = 0; j < 4; ++j) {
    gload_lds16(aptr[j], &As[0][(wid * 32 + j * 8) * 64]);
    gload_lds16(bptr[j], &Bs[0][(wid * 32 + j * 8) * 64]);
    aptr[j] += 64; bptr[j] += 64;
  }
  __syncthreads();

  int cur = 0;
  for (int kt = 0; kt < 12; ++kt) {
    if (kt < 11) {
#pragma unroll
      for (int j = 0; j < 4; ++j) {
        gload_lds16(aptr[j], &As[cur ^ 1][(wid * 32 + j * 8) * 64]);
        gload_lds16(bptr[j], &Bs[cur ^ 1][(wid * 32 + j * 8) * 64]);
        aptr[j] += 64; bptr[j] += 64;
      }
    }

    bf16x8 af[2][4], bfr[2][4];
#pragma unroll
    for (int kf = 0; kf < 2; ++kf)
#pragma unroll
      for (int mf = 0; mf < 4; ++mf)
        af[kf][mf] = *(const bf16x8*)&As[cur][(wm * 64 + mf * 16 + (lane & 15)) * 64 + ((kf * 32 + (lane >> 4) * 8) ^ axor)];
#pragma unroll
    for (int kf = 0; kf < 2; ++kf)
#pragma unroll
      for (int nf = 0; nf < 4; ++nf)
        bfr[kf][nf] = *(const bf16x8*)&Bs[cur][(wn * 64 + nf * 16 + (lane & 15)) * 64 + ((kf * 32 + (lane >> 4) * 8) ^ axor)];

#pragma unroll
    for (int mf = 0; mf < 4; ++mf)
#pragma unroll
      for (int nf = 0; nf < 4; ++nf) {
        acc[mf][nf] = __builtin_amdgcn_mfma_f32_16x16x32_bf16(af[0][mf], bfr[0][nf], acc[mf][nf], 0, 0, 0);
        acc[mf][nf] = __builtin_amdgcn_mfma_f32_16x16x32_bf16(af[1][mf], bfr[1][nf], acc[mf][nf], 0, 0, 0);
      }
    __syncthreads();
    cur ^= 1;
  }

  u16* dst = (n0 < 768 ? ps : ts) + (size_t)b * MPAD * DD;
  const float* cv = (n0 < 768 ? cp : ct) + b * DD;
  const int ncol0 = n0 - (n0 < 768 ? 0 : 768);
#pragma unroll
  for (int mf = 0; mf < 4; ++mf)
#pragma unroll
    for (int nf = 0; nf < 4; ++nf)
#pragma unroll
      for (int r = 0; r < 4; ++r) {
        int row = m0 + wm * 64 + mf * 16 + (lane >> 4) * 4 + r;
        int col = ncol0 + wn * 64 + nf * 16 + (lane & 15);
        dst[(size_t)row * DD + col] = f2bf(acc[mf][nf][r] + cv[col]);
      }
}

// ---------------- table max ----------------
__global__ void table_max_kernel(const u16* __restrict__ ts, const int* __restrict__ ids,
                                 u16* __restrict__ tmax) {
  int bi = blockIdx.x;  // 4*60*3 = 720
  int b = bi / 180;
  int rem = bi % 180;
  int tok = rem / 3;
  int dc = rem % 3;
  int d = dc * 256 + threadIdx.x;
  __shared__ int sids[100];
  if (threadIdx.x < 100) sids[threadIdx.x] = ids[b * 100 + threadIdx.x];
  __syncthreads();
  float m[NUM_TABLES];
#pragma unroll
  for (int t = 0; t < NUM_TABLES; ++t) m[t] = -INFINITY;
  const u16* base = ts + ((size_t)b * MPAD + tok) * DD + d;
  for (int p = 0; p < 100; ++p) {
    float v = bf2f(base[(size_t)p * 60 * DD]);
    int id = sids[p];
#pragma unroll
    for (int t = 0; t < NUM_TABLES; ++t)
      if (id == t) m[t] = fmaxf(m[t], v);
  }
#pragma unroll
  for (int t = 0; t < NUM_TABLES; ++t)
    tmax[(((size_t)b * NUM_TABLES + t) * 60 + tok) * DD + d] = f2bf(m[t]);
}

// ---------------- gemm_t: Ht = tmax @ Wf1_hi^T (f32 out) ----------------
// M=640 (600 real rows, A-ptr clamped), N=768, K=768. Grid 120 XCD-chunked.
__global__ __launch_bounds__(256, 2)
void gemm_t(const u16* __restrict__ tmax, const u16* __restrict__ Wf1b,
            float* __restrict__ Ht) {
  int flat = blockIdx.x;
  int lid = (flat & 7) * 15 + (flat >> 3);
  int n = lid % 6;
  int m = (lid / 6) % 5;
  int b = lid / 30;

  const int m0 = m * 128;
  const int n0 = n * 128;
  const int tid = threadIdx.x;
  const int lane = tid & 63;
  const int wid = tid >> 6;
  const int wm = wid >> 1, wn = wid & 1;

  __shared__ u16 As[2][128 * 64];
  __shared__ u16 Bs[2][128 * 64];

  const u16* Abase = tmax + (size_t)b * 600 * DD;

  f32x4 acc[4][4] = {};

  const int lrow = lane >> 3;
  const int lcol_s = (((lane & 7) ^ (lrow & 7)) * 8);
  const int axor = (lane & 7) << 3;

  const u16* aptr[4];
  const u16* bptr[4];
#pragma unroll
  for (int j = 0; j < 4; ++j) {
    int row = m0 + wid * 32 + j * 8 + lrow;
    int rp = row < 600 ? row : 599;  // clamp pad rows
    aptr[j] = Abase + (size_t)rp * DD + lcol_s;
    bptr[j] = Wf1b + (size_t)(n0 + wid * 32 + j * 8 + lrow) * 1536 + 768 + lcol_s;
  }

#pragma unroll
  for (int j = 0; j < 4; ++j) {
    gload_lds16(aptr[j], &As[0][(wid * 32 + j * 8) * 64]);
    gload_lds16(bptr[j], &Bs[0][(wid * 32 + j * 8) * 64]);
    aptr[j] += 64; bptr[j] += 64;
  }
  __syncthreads();

  int cur = 0;
  for (int kt = 0; kt < 12; ++kt) {
    if (kt < 11) {
#pragma unroll
      for (int j = 0; j < 4; ++j) {
        gload_lds16(aptr[j], &As[cur ^ 1][(wid * 32 + j * 8) * 64]);
        gload_lds16(bptr[j], &Bs[cur ^ 1][(wid * 32 + j * 8) * 64]);
        aptr[j] += 64; bptr[j] += 64;
      }
    }

    bf16x8 af[2][4], bfr[2][4];
#pragma unroll
    for (int kf = 0; kf < 2; ++kf)
#pragma unroll
      for (int mf = 0; mf < 4; ++mf)
        af[kf][mf] = *(const bf16x8*)&As[cur][(wm * 64 + mf * 16 + (lane & 15)) * 64 + ((kf * 32 + (lane >> 4) * 8) ^ axor)];
#pragma unroll
    for (int kf = 0; kf < 2; ++kf)
#pragma unroll
      for (int nf = 0; nf < 4; ++nf)
        bfr[kf][nf] = *(const bf16x8*)&Bs[cur][(wn * 64 + nf * 16 + (lane & 15)) * 64 + ((kf * 32 + (lane >> 4) * 8) ^ axor)];

#pragma unroll
    for (int mf = 0; mf < 4; ++mf)
#pragma unroll
      for (int nf = 0; nf < 4; ++nf) {
        acc[mf][nf] = __builtin_amdgcn_mfma_f32_16x16x32_bf16(af[0][mf], bfr[0][nf], acc[mf][nf], 0, 0, 0);
        acc[mf][nf] = __builtin_amdgcn_mfma_f32_16x16x32_bf16(af[1][mf], bfr[1][nf], acc[mf][nf], 0, 0, 0);
      }
    __syncthreads();
    cur ^= 1;
  }

  float* Hb = Ht + (size_t)b * 640 * DD;
#pragma unroll
  for (int mf = 0; mf < 4; ++mf)
#pragma unroll
    for (int nf = 0; nf < 4; ++nf)
#pragma unroll
      for (int r = 0; r < 4; ++r) {
        int row = m0 + wm * 64 + mf * 16 + (lane >> 4) * 4 + r;
        int col = n0 + wn * 64 + nf * 16 + (lane & 15);
        Hb[(size_t)row * DD + col] = acc[mf][nf][r];
      }
}

// ---------------- gemm_h: Hp = ps @ Wf1_lo^T + fused score ----------------
// K=768 single source; epilogue H = Hp + Ht[gather] + bf1 -> relu -> dot w2.
__global__ __launch_bounds__(256, 2)
void gemm_h(const u16* __restrict__ ps, const float* __restrict__ Ht,
            const int* __restrict__ ids, const u16* __restrict__ Wf1b,
            const float* __restrict__ bf1, const float* __restrict__ w2,
            const float* __restrict__ mask, float* __restrict__ out) {
  int flat = blockIdx.x;
  int lid = (flat & 7) * 141 + (flat >> 3);
  int n = lid % 6;
  int m = (lid / 6) % 47;
  int b = lid / 282;

  const int m0 = m * 128;
  const int n0 = n * 128;
  const int tid = threadIdx.x;
  const int lane = tid & 63;
  const int wid = tid >> 6;
  const int wm = wid >> 1, wn = wid & 1;

  __shared__ u16 As[2][128 * 64];
  __shared__ u16 Bs[2][128 * 64];
  __shared__ int sids[100];
  __shared__ float pacc[4];
  if (tid < 100) sids[tid] = ids[b * 100 + tid];
  if (tid < 4) pacc[tid] = 0.f;
  __syncthreads();

  const u16* Abase = ps + (size_t)b * MPAD * DD;

  f32x4 acc[4][4] = {};

  const int lrow = lane >> 3;
  const int lcol_s = (((lane & 7) ^ (lrow & 7)) * 8);
  const int axor = (lane & 7) << 3;

  const u16* aptr[4];
  const u16* bptr[4];
#pragma unroll
  for (int j = 0; j < 4; ++j) {
    aptr[j] = Abase + (size_t)(m0 + wid * 32 + j * 8 + lrow) * DD + lcol_s;
    bptr[j] = Wf1b + (size_t)(n0 + wid * 32 + j * 8 + lrow) * 1536 + lcol_s;
  }

#pragma unroll
  for (int j = 0; j < 4; ++j) {
    gload_lds16(aptr[j], &As[0][(wid * 32 + j * 8) * 64]);
    gload_lds16(bptr[j], &Bs[0][(wid * 32 + j * 8) * 64]);
    aptr[j] += 64; bptr[j] += 64;
  }
  __syncthreads();

  int cur = 0;
  for (int kt = 0; kt < 12; ++kt) {
    if (kt < 11) {
#pragma unroll
      for (int j = 0; j < 4; ++j) {
        gload_lds16(aptr[j], &As[cur ^ 1][(wid * 32 + j * 8) * 64]);
        gload_lds16(bptr[j], &Bs[cur ^ 1][(wid * 32 + j * 8) * 64]);
        aptr[j] += 64; bptr[j] += 64;
      }
    }

    bf16x8 af[2][4], bfr[2][4];
#pragma unroll
    for (int kf = 0; kf < 2; ++kf)
#pragma unroll
      for (int mf = 0; mf < 4; ++mf)
        af[kf][mf] = *(const bf16x8*)&As[cur][(wm * 64 + mf * 16 + (lane & 15)) * 64 + ((kf * 32 + (lane >> 4) * 8) ^ axor)];
#pragma unroll
    for (int kf = 0; kf < 2; ++kf)
#pragma unroll
      for (int nf = 0; nf < 4; ++nf)
        bfr[kf][nf] = *(const bf16x8*)&Bs[cur][(wn * 64 + nf * 16 + (lane & 15)) * 64 + ((kf * 32 + (lane >> 4) * 8) ^ axor)];

#pragma unroll
    for (int mf = 0; mf < 4; ++mf)
#pragma unroll
      for (int nf = 0; nf < 4; ++nf) {
        acc[mf][nf] = __builtin_amdgcn_mfma_f32_16x16x32_bf16(af[0][mf], bfr[0][nf], acc[mf][nf], 0, 0, 0);
        acc[mf][nf] = __builtin_amdgcn_mfma_f32_16x16x32_bf16(af[1][mf], bfr[1][nf], acc[mf][nf], 0, 0, 0);
      }
    __syncthreads();
    cur ^= 1;
  }

  // fused score epilogue: H = Hp + Ht[gather] + bf1
  float b1v[4], w2v[4];
  int cbase = n0 + wn * 64 + (lane & 15);
#pragma unroll
  for (int nf = 0; nf < 4; ++nf) {
    b1v[nf] = bf1[cbase + nf * 16];
    w2v[nf] = w2[cbase + nf * 16];
  }
  const float* Hb = Ht + (size_t)b * 640 * DD;
  const int pfirst = m0 / 60;
#pragma unroll
  for (int mf = 0; mf < 4; ++mf)
#pragma unroll
    for (int r = 0; r < 4; ++r) {
      int row = m0 + wm * 64 + mf * 16 + (lane >> 4) * 4 + r;
      if (row < 6000) {
        int p = (unsigned)row / 60u;
        int tok = row - p * 60;
        const float* htrow = Hb + (size_t)(sids[p] * 60 + tok) * DD + cbase;
        float s = 0.f;
#pragma unroll
        for (int nf = 0; nf < 4; ++nf)
          s += fmaxf(acc[mf][nf][r] + htrow[nf * 16] + b1v[nf], 0.f) * w2v[nf];
        s += __shfl_xor(s, 1);
        s += __shfl_xor(s, 2);
        s += __shfl_xor(s, 4);
        s += __shfl_xor(s, 8);
        if ((lane & 15) == 0) {
          float mk = mask[((size_t)b * 100 + p) * 60 + tok];
          atomicAdd(&pacc[p - pfirst], mk * s);
        }
      }
    }
  __syncthreads();
  int plast = (m0 + 127 < 6000 ? m0 + 127 : 5999) / 60;
  if (tid <= plast - pfirst)
    atomicAdd(out + b * 100 + pfirst + tid, pacc[tid]);
}

// ---------------- launch ----------------
extern "C" void kernel_launch(void* const* d_in, const int* in_sizes, int n_in,
                              void* d_out, int out_size, void* d_ws, size_t ws_size,
                              hipStream_t stream) {
  const float* answer = (const float*)d_in[0];
  const float* qps    = (const float*)d_in[1];
  const float* mask   = (const float*)d_in[2];
  const int*   tids   = (const int*)d_in[3];
  const float* Wp     = (const float*)d_in[4];
  const float* bp     = (const float*)d_in[5];
  const float* Wt     = (const float*)d_in[6];
  const float* bt     = (const float*)d_in[7];
  const float* Wf1    = (const float*)d_in[8];
  const float* bf1    = (const float*)d_in[9];
  const float* Wf2    = (const float*)d_in[10];
  const float* bf2    = (const float*)d_in[11];
  float* out = (float*)d_out;

  char* ws = (char*)d_ws;
  // region layout (bytes); total 126,394,368.
  // tmax (3,686,400) and Ht (7,864,320) alias Qpad (dead after gemm12).
  u16* Qpad = (u16*)(ws + 0);            // 36,962,304
  u16* ps   = (u16*)(ws + 36962304);     // 36,962,304
  u16* ts   = (u16*)(ws + 73924608);     // 36,962,304
  u16* Bcat = (u16*)(ws + 110886912);    // 9,437,184
  u16* Wf1b = (u16*)(ws + 120324096);    // 2,359,296
  float* cp = (float*)(ws + 122683392);  // 12,288
  float* ct = (float*)(ws + 122695680);  // 12,288
  u16* tmax = (u16*)(ws + 0);            // [4][600][768] bf16 (aliases Qpad)
  float* Ht = (float*)(ws + 4194304);    // [4][640][768] f32  (aliases Qpad)

  prep_all<<<13442, 256, 0, stream>>>(qps, (uint4*)Qpad, answer, Wp, Wt, Bcat,
                                      Wf1, (uint4*)Wf1b, bp, bt, cp, ct,
                                      mask, bf2, out);

  gemm12<<<2256, 256, 0, stream>>>(Qpad, Bcat, cp, ct, ps, ts);

  table_max_kernel<<<720, 256, 0, stream>>>(ts, tids, tmax);

  gemm_t<<<120, 256, 0, stream>>>(tmax, Wf1b, Ht);

  gemm_h<<<1128, 256, 0, stream>>>(ps, Ht, tids, Wf1b, bf1, Wf2, mask, out);
}

// Round 8
// 214.426 us; speedup vs baseline: 1.3298x; 1.0584x over previous
//
#include <hip/hip_runtime.h>
#include <hip/hip_bf16.h>

// FusionRetrModel: B=4, NL=2 (only l=1 used), P=100, TOK=60, T=6000, D=768.
// R8 pipeline (full linear factorization — ps is never materialized):
//   prep_all: Qpad bf16 [4][6016][768]; Wtb; WpbT (LDS-tiled transpose);
//             Wf1 cast; cp/ct GEMV; out init = bf2*msum.
//   gemm_ts: ts = Qpad @ Wtb^T + ct              (K=768; needed for max)
//   gemm_wc: Wcomb[b] = Wf1_lo @ Wpb[b]          (via WpbT; 768^3 x4, bf16 out)
//   prep2:   bf1x[b][c] = bf1[c] + Wf1_lo @ cp[b]
//   tmax:    per-table max over passages (600 rows/batch)
//   gemm_t:  Ht = tmax @ Wf1_hi^T  (f32, M=640 pad)
//   gemm_h:  Hcore = Qpad @ Wcomb^T; epilogue H = Hcore + Ht[gather] + bf1x,
//            relu, dot w2, mask-weighted per-passage reduce -> atomicAdd out.
// All GEMMs: 128^2 tile, BK=64, dbuf 2-phase, T2 swizzle (src-side), 0 conflicts.
// Workspace: ~102 MB.

typedef unsigned short u16;
typedef unsigned int u32;
typedef __attribute__((ext_vector_type(8))) short bf16x8;
typedef __attribute__((ext_vector_type(4))) float f32x4;

#define NUM_TABLES 10
#define MPAD 6016
#define DD 768

__device__ __forceinline__ u16 f2bf(float f) {
  u32 u = __builtin_bit_cast(u32, f);
  u32 r = u + 0x7FFFu + ((u >> 16) & 1u);
  return (u16)(r >> 16);
}
__device__ __forceinline__ float bf2f(u16 h) {
  u32 u = ((u32)h) << 16;
  return __builtin_bit_cast(float, u);
}

__device__ __forceinline__ void gload_lds16(const u16* g, u16* l) {
  __builtin_amdgcn_global_load_lds(
      (const __attribute__((address_space(1))) void*)g,
      (__attribute__((address_space(3))) void*)l, 16, 0, 0);
}

// ---------------- fused prep (one dispatch) ----------------
__global__ void prep_all(const float* __restrict__ qps, uint4* __restrict__ qpad,
                         const float* __restrict__ Ans, const float* __restrict__ Wp,
                         const float* __restrict__ Wt, u16* __restrict__ Wtb,
                         u16* __restrict__ WpbT,
                         const float* __restrict__ Wf1, uint4* __restrict__ Wf1b,
                         const float* __restrict__ bp, const float* __restrict__ bt,
                         float* __restrict__ cp, float* __restrict__ ct,
                         const float* __restrict__ mask, const float* __restrict__ bf2,
                         float* __restrict__ out) {
  int blk = blockIdx.x;
  int tid = threadIdx.x;
  if (blk < 9024) {
    // ---- Qpad: cast l=1 slice to bf16, pad rows [6000,6016) ----
    size_t c = (size_t)blk * 256 + tid;
    const int per_b = MPAD * (DD / 8);
    int b = (int)(c / per_b);
    int rr = (int)(c % per_b);
    int r = rr / (DD / 8);
    int kc = rr % (DD / 8);
    uint4 o;
    if (r < 6000) {
      const float* src = qps + (((size_t)(b * 2 + 1)) * 6000 + r) * DD + kc * 8;
      float4 f0 = *(const float4*)src;
      float4 f1 = *(const float4*)(src + 4);
      o.x = (u32)f2bf(f0.x) | ((u32)f2bf(f0.y) << 16);
      o.y = (u32)f2bf(f0.z) | ((u32)f2bf(f0.w) << 16);
      o.z = (u32)f2bf(f1.x) | ((u32)f2bf(f1.y) << 16);
      o.w = (u32)f2bf(f1.z) | ((u32)f2bf(f1.w) << 16);
    } else {
      o = make_uint4(0, 0, 0, 0);
    }
    qpad[c] = o;
  } else if (blk < 10176) {
    // ---- Wtb[b][d][k] = Wt[d][768+k] + A[b][k]*Wt[d][1536+k], 8 k/thread ----
    size_t c = (size_t)(blk - 9024) * 256 + tid;
    const int per_b = DD * (DD / 8);  // 73728
    int b = (int)(c / per_b);
    int rr = (int)(c % per_b);
    int d = rr / (DD / 8);
    int k8 = (rr % (DD / 8)) * 8;
    const float* a = Ans + ((size_t)b * 2 + 1) * DD + k8;
    const float* w2r = Wt + (size_t)d * 2304 + 768 + k8;
    const float* w3r = Wt + (size_t)d * 2304 + 1536 + k8;
    float4 a0 = *(const float4*)a, a1 = *(const float4*)(a + 4);
    float4 t20 = *(const float4*)w2r, t21 = *(const float4*)(w2r + 4);
    float4 t30 = *(const float4*)w3r, t31 = *(const float4*)(w3r + 4);
    uint4 o;
    o.x = (u32)f2bf(t20.x + a0.x * t30.x) | ((u32)f2bf(t20.y + a0.y * t30.y) << 16);
    o.y = (u32)f2bf(t20.z + a0.z * t30.z) | ((u32)f2bf(t20.w + a0.w * t30.w) << 16);
    o.z = (u32)f2bf(t21.x + a1.x * t31.x) | ((u32)f2bf(t21.y + a1.y * t31.y) << 16);
    o.w = (u32)f2bf(t21.z + a1.z * t31.z) | ((u32)f2bf(t21.w + a1.w * t31.w) << 16);
    *(uint4*)(Wtb + ((size_t)b * DD + d) * DD + k8) = o;
  } else if (blk < 10752) {
    // ---- WpbT[b][k][d] = Wp[d][768+k] + A[b][k]*Wp[d][1536+k] (LDS transpose) ----
    int tb = blk - 10176;          // 0..575
    int b = tb / 144;
    int tt = tb % 144;
    int k0 = (tt / 12) * 64, d0 = (tt % 12) * 64;
    __shared__ u16 tile[64][72];   // [k][d], padded row
    int kc = tid & 63;             // k within tile
    int r0 = tid >> 6;             // 0..3
    float av = Ans[((size_t)b * 2 + 1) * DD + k0 + kc];
#pragma unroll
    for (int it = 0; it < 16; ++it) {
      int dr = it * 4 + r0;        // d within tile
      const float* wrow = Wp + (size_t)(d0 + dr) * 2304;
      float v = wrow[768 + k0 + kc] + av * wrow[1536 + k0 + kc];
      tile[kc][dr] = f2bf(v);
    }
    __syncthreads();
#pragma unroll
    for (int it = 0; it < 2; ++it) {
      int kk = it * 32 + (tid >> 3);
      int dd = (tid & 7) * 8;
      *(uint4*)(WpbT + ((size_t)b * DD + k0 + kk) * DD + d0 + dd) =
          *(const uint4*)&tile[kk][dd];
    }
  } else if (blk < 11328) {
    // ---- Wf1 cast ----
    size_t c = (size_t)(blk - 10752) * 256 + tid;
    const float* src = Wf1 + c * 8;
    float4 f0 = *(const float4*)src;
    float4 f1 = *(const float4*)(src + 4);
    uint4 o;
    o.x = (u32)f2bf(f0.x) | ((u32)f2bf(f0.y) << 16);
    o.y = (u32)f2bf(f0.z) | ((u32)f2bf(f0.w) << 16);
    o.z = (u32)f2bf(f1.x) | ((u32)f2bf(f1.y) << 16);
    o.w = (u32)f2bf(f1.z) | ((u32)f2bf(f1.w) << 16);
    Wf1b[c] = o;
  } else if (blk < 12864) {
    // ---- cp/ct parallel: one block per (matrix, d) ----
    int e = blk - 11328;          // 0..1535
    int isT = e >= 768;
    int d = e - (isT ? 768 : 0);
    const float* wrow = (isT ? Wt : Wp) + (size_t)d * 2304;
    float a0 = 0.f, a1 = 0.f, a2 = 0.f, a3 = 0.f;
    for (int k = tid; k < DD; k += 256) {
      float w = wrow[k];
      a0 += w * Ans[1 * DD + k];
      a1 += w * Ans[3 * DD + k];
      a2 += w * Ans[5 * DD + k];
      a3 += w * Ans[7 * DD + k];
    }
#pragma unroll
    for (int off = 32; off > 0; off >>= 1) {
      a0 += __shfl_down(a0, off);
      a1 += __shfl_down(a1, off);
      a2 += __shfl_down(a2, off);
      a3 += __shfl_down(a3, off);
    }
    __shared__ float red[4][4];
    int wid = tid >> 6;
    if ((tid & 63) == 0) {
      red[wid][0] = a0; red[wid][1] = a1; red[wid][2] = a2; red[wid][3] = a3;
    }
    __syncthreads();
    if (tid < 4) {
      float s = red[0][tid] + red[1][tid] + red[2][tid] + red[3][tid];
      float bias = (isT ? bt : bp)[d];
      (isT ? ct : cp)[tid * DD + d] = s + bias;
    }
  } else {
    // ---- out init = bf2 * msum ----
    int idx = (blk - 12864) * 256 + tid;
    if (idx >= 400) return;
    const float* m = mask + (size_t)idx * 60;
    float s = 0.f;
    for (int t = 0; t < 60; ++t) s += m[t];
    out[idx] = bf2[0] * s;
  }
}

// ---------------- prep2: bf1x[b][c] = bf1[c] + Wf1_lo[c,:] . cp[b,:] ----------------
__global__ void prep2(const float* __restrict__ Wf1, const float* __restrict__ cp,
                      const float* __restrict__ bf1, float* __restrict__ bf1x) {
  int c = blockIdx.x;
  int tid = threadIdx.x;
  const float* wrow = Wf1 + (size_t)c * 1536;
  float a0 = 0.f, a1 = 0.f, a2 = 0.f, a3 = 0.f;
  for (int d = tid; d < DD; d += 256) {
    float w = wrow[d];
    a0 += w * cp[0 * DD + d];
    a1 += w * cp[1 * DD + d];
    a2 += w * cp[2 * DD + d];
    a3 += w * cp[3 * DD + d];
  }
#pragma unroll
  for (int off = 32; off > 0; off >>= 1) {
    a0 += __shfl_down(a0, off);
    a1 += __shfl_down(a1, off);
    a2 += __shfl_down(a2, off);
    a3 += __shfl_down(a3, off);
  }
  __shared__ float red[4][4];
  int wid = tid >> 6;
  if ((tid & 63) == 0) {
    red[wid][0] = a0; red[wid][1] = a1; red[wid][2] = a2; red[wid][3] = a3;
  }
  __syncthreads();
  if (tid < 4) {
    float s = red[0][tid] + red[1][tid] + red[2][tid] + red[3][tid];
    bf1x[tid * DD + c] = bf1[c] + s;
  }
}

// ---------------- gemm_ts: ts = Qpad @ Wtb^T + ct ----------------
__global__ __launch_bounds__(256, 2)
void gemm_ts(const u16* __restrict__ Q, const u16* __restrict__ Wtb,
             const float* __restrict__ ct, u16* __restrict__ ts) {
  int flat = blockIdx.x;
  int lid = (flat & 7) * 141 + (flat >> 3);
  int n = lid % 6;
  int m = (lid / 6) % 47;
  int b = lid / 282;

  const int m0 = m * 128;
  const int n0 = n * 128;
  const int tid = threadIdx.x;
  const int lane = tid & 63;
  const int wid = tid >> 6;
  const int wm = wid >> 1, wn = wid & 1;

  __shared__ u16 As[2][128 * 64];
  __shared__ u16 Bs[2][128 * 64];

  const u16* Abase = Q + (size_t)b * MPAD * DD;
  const u16* Bbase = Wtb + (size_t)b * DD * DD;

  f32x4 acc[4][4] = {};

  const int lrow = lane >> 3;
  const int lcol_s = (((lane & 7) ^ (lrow & 7)) * 8);
  const int axor = (lane & 7) << 3;

  const u16* aptr[4];
  const u16* bptr[4];
#pragma unroll
  for (int j = 0; j < 4; ++j) {
    aptr[j] = Abase + (size_t)(m0 + wid * 32 + j * 8 + lrow) * DD + lcol_s;
    bptr[j] = Bbase + (size_t)(n0 + wid * 32 + j * 8 + lrow) * DD + lcol_s;
  }

#pragma unroll
  for (int j = 0; j < 4; ++j) {
    gload_lds16(aptr[j], &As[0][(wid * 32 + j * 8) * 64]);
    gload_lds16(bptr[j], &Bs[0][(wid * 32 + j * 8) * 64]);
    aptr[j] += 64; bptr[j] += 64;
  }
  __syncthreads();

  int cur = 0;
  for (int kt = 0; kt < 12; ++kt) {
    if (kt < 11) {
#pragma unroll
      for (int j = 0; j < 4; ++j) {
        gload_lds16(aptr[j], &As[cur ^ 1][(wid * 32 + j * 8) * 64]);
        gload_lds16(bptr[j], &Bs[cur ^ 1][(wid * 32 + j * 8) * 64]);
        aptr[j] += 64; bptr[j] += 64;
      }
    }
    bf16x8 af[2][4], bfr[2][4];
#pragma unroll
    for (int kf = 0; kf < 2; ++kf)
#pragma unroll
      for (int mf = 0; mf < 4; ++mf)
        af[kf][mf] = *(const bf16x8*)&As[cur][(wm * 64 + mf * 16 + (lane & 15)) * 64 + ((kf * 32 + (lane >> 4) * 8) ^ axor)];
#pragma unroll
    for (int kf = 0; kf < 2; ++kf)
#pragma unroll
      for (int nf = 0; nf < 4; ++nf)
        bfr[kf][nf] = *(const bf16x8*)&Bs[cur][(wn * 64 + nf * 16 + (lane & 15)) * 64 + ((kf * 32 + (lane >> 4) * 8) ^ axor)];
#pragma unroll
    for (int mf = 0; mf < 4; ++mf)
#pragma unroll
      for (int nf = 0; nf < 4; ++nf) {
        acc[mf][nf] = __builtin_amdgcn_mfma_f32_16x16x32_bf16(af[0][mf], bfr[0][nf], acc[mf][nf], 0, 0, 0);
        acc[mf][nf] = __builtin_amdgcn_mfma_f32_16x16x32_bf16(af[1][mf], bfr[1][nf], acc[mf][nf], 0, 0, 0);
      }
    __syncthreads();
    cur ^= 1;
  }

  u16* dst = ts + (size_t)b * MPAD * DD;
  const float* cv = ct + b * DD;
#pragma unroll
  for (int mf = 0; mf < 4; ++mf)
#pragma unroll
    for (int nf = 0; nf < 4; ++nf)
#pragma unroll
      for (int r = 0; r < 4; ++r) {
        int row = m0 + wm * 64 + mf * 16 + (lane >> 4) * 4 + r;
        int col = n0 + wn * 64 + nf * 16 + (lane & 15);
        dst[(size_t)row * DD + col] = f2bf(acc[mf][nf][r] + cv[col]);
      }
}

// ---------------- gemm_wc: Wcomb[b][c][k] = sum_d Wf1_lo[c][d] * WpbT[b][k][d] ----------------
__global__ __launch_bounds__(256, 2)
void gemm_wc(const u16* __restrict__ Wf1b, const u16* __restrict__ WpbT,
             u16* __restrict__ Wcomb) {
  int flat = blockIdx.x;   // 144 = 8*18
  int lid = (flat & 7) * 18 + (flat >> 3);
  int n = lid % 6;
  int m = (lid / 6) % 6;
  int b = lid / 36;

  const int m0 = m * 128;
  const int n0 = n * 128;
  const int tid = threadIdx.x;
  const int lane = tid & 63;
  const int wid = tid >> 6;
  const int wm = wid >> 1, wn = wid & 1;

  __shared__ u16 As[2][128 * 64];
  __shared__ u16 Bs[2][128 * 64];

  const u16* Bbase = WpbT + (size_t)b * DD * DD;

  f32x4 acc[4][4] = {};

  const int lrow = lane >> 3;
  const int lcol_s = (((lane & 7) ^ (lrow & 7)) * 8);
  const int axor = (lane & 7) << 3;

  const u16* aptr[4];
  const u16* bptr[4];
#pragma unroll
  for (int j = 0; j < 4; ++j) {
    aptr[j] = Wf1b + (size_t)(m0 + wid * 32 + j * 8 + lrow) * 1536 + lcol_s;
    bptr[j] = Bbase + (size_t)(n0 + wid * 32 + j * 8 + lrow) * DD + lcol_s;
  }

#pragma unroll
  for (int j = 0; j < 4; ++j) {
    gload_lds16(aptr[j], &As[0][(wid * 32 + j * 8) * 64]);
    gload_lds16(bptr[j], &Bs[0][(wid * 32 + j * 8) * 64]);
    aptr[j] += 64; bptr[j] += 64;
  }
  __syncthreads();

  int cur = 0;
  for (int kt = 0; kt < 12; ++kt) {
    if (kt < 11) {
#pragma unroll
      for (int j = 0; j < 4; ++j) {
        gload_lds16(aptr[j], &As[cur ^ 1][(wid * 32 + j * 8) * 64]);
        gload_lds16(bptr[j], &Bs[cur ^ 1][(wid * 32 + j * 8) * 64]);
        aptr[j] += 64; bptr[j] += 64;
      }
    }
    bf16x8 af[2][4], bfr[2][4];
#pragma unroll
    for (int kf = 0; kf < 2; ++kf)
#pragma unroll
      for (int mf = 0; mf < 4; ++mf)
        af[kf][mf] = *(const bf16x8*)&As[cur][(wm * 64 + mf * 16 + (lane & 15)) * 64 + ((kf * 32 + (lane >> 4) * 8) ^ axor)];
#pragma unroll
    for (int kf = 0; kf < 2; ++kf)
#pragma unroll
      for (int nf = 0; nf < 4; ++nf)
        bfr[kf][nf] = *(const bf16x8*)&Bs[cur][(wn * 64 + nf * 16 + (lane & 15)) * 64 + ((kf * 32 + (lane >> 4) * 8) ^ axor)];
#pragma unroll
    for (int mf = 0; mf < 4; ++mf)
#pragma unroll
      for (int nf = 0; nf < 4; ++nf) {
        acc[mf][nf] = __builtin_amdgcn_mfma_f32_16x16x32_bf16(af[0][mf], bfr[0][nf], acc[mf][nf], 0, 0, 0);
        acc[mf][nf] = __builtin_amdgcn_mfma_f32_16x16x32_bf16(af[1][mf], bfr[1][nf], acc[mf][nf], 0, 0, 0);
      }
    __syncthreads();
    cur ^= 1;
  }

  u16* Cb = Wcomb + (size_t)b * DD * DD;
#pragma unroll
  for (int mf = 0; mf < 4; ++mf)
#pragma unroll
    for (int nf = 0; nf < 4; ++nf)
#pragma unroll
      for (int r = 0; r < 4; ++r) {
        int row = m0 + wm * 64 + mf * 16 + (lane >> 4) * 4 + r;
        int col = n0 + wn * 64 + nf * 16 + (lane & 15);
        Cb[(size_t)row * DD + col] = f2bf(acc[mf][nf][r]);
      }
}

// ---------------- table max ----------------
__global__ void table_max_kernel(const u16* __restrict__ ts, const int* __restrict__ ids,
                                 u16* __restrict__ tmax) {
  int bi = blockIdx.x;  // 720
  int b = bi / 180;
  int rem = bi % 180;
  int tok = rem / 3;
  int dc = rem % 3;
  int d = dc * 256 + threadIdx.x;
  __shared__ int sids[100];
  if (threadIdx.x < 100) sids[threadIdx.x] = ids[b * 100 + threadIdx.x];
  __syncthreads();
  float m[NUM_TABLES];
#pragma unroll
  for (int t = 0; t < NUM_TABLES; ++t) m[t] = -INFINITY;
  const u16* base = ts + ((size_t)b * MPAD + tok) * DD + d;
  for (int p = 0; p < 100; ++p) {
    float v = bf2f(base[(size_t)p * 60 * DD]);
    int id = sids[p];
#pragma unroll
    for (int t = 0; t < NUM_TABLES; ++t)
      if (id == t) m[t] = fmaxf(m[t], v);
  }
#pragma unroll
  for (int t = 0; t < NUM_TABLES; ++t)
    tmax[(((size_t)b * NUM_TABLES + t) * 60 + tok) * DD + d] = f2bf(m[t]);
}

// ---------------- gemm_t: Ht = tmax @ Wf1_hi^T (f32 out) ----------------
__global__ __launch_bounds__(256, 2)
void gemm_t(const u16* __restrict__ tmax, const u16* __restrict__ Wf1b,
            float* __restrict__ Ht) {
  int flat = blockIdx.x;   // 120 = 8*15
  int lid = (flat & 7) * 15 + (flat >> 3);
  int n = lid % 6;
  int m = (lid / 6) % 5;
  int b = lid / 30;

  const int m0 = m * 128;
  const int n0 = n * 128;
  const int tid = threadIdx.x;
  const int lane = tid & 63;
  const int wid = tid >> 6;
  const int wm = wid >> 1, wn = wid & 1;

  __shared__ u16 As[2][128 * 64];
  __shared__ u16 Bs[2][128 * 64];

  const u16* Abase = tmax + (size_t)b * 600 * DD;

  f32x4 acc[4][4] = {};

  const int lrow = lane >> 3;
  const int lcol_s = (((lane & 7) ^ (lrow & 7)) * 8);
  const int axor = (lane & 7) << 3;

  const u16* aptr[4];
  const u16* bptr[4];
#pragma unroll
  for (int j = 0; j < 4; ++j) {
    int row = m0 + wid * 32 + j * 8 + lrow;
    int rp = row < 600 ? row : 599;
    aptr[j] = Abase + (size_t)rp * DD + lcol_s;
    bptr[j] = Wf1b + (size_t)(n0 + wid * 32 + j * 8 + lrow) * 1536 + 768 + lcol_s;
  }

#pragma unroll
  for (int j = 0; j < 4; ++j) {
    gload_lds16(aptr[j], &As[0][(wid * 32 + j * 8) * 64]);
    gload_lds16(bptr[j], &Bs[0][(wid * 32 + j * 8) * 64]);
    aptr[j] += 64; bptr[j] += 64;
  }
  __syncthreads();

  int cur = 0;
  for (int kt = 0; kt < 12; ++kt) {
    if (kt < 11) {
#pragma unroll
      for (int j = 0; j < 4; ++j) {
        gload_lds16(aptr[j], &As[cur ^ 1][(wid * 32 + j * 8) * 64]);
        gload_lds16(bptr[j], &Bs[cur ^ 1][(wid * 32 + j * 8) * 64]);
        aptr[j] += 64; bptr[j] += 64;
      }
    }
    bf16x8 af[2][4], bfr[2][4];
#pragma unroll
    for (int kf = 0; kf < 2; ++kf)
#pragma unroll
      for (int mf = 0; mf < 4; ++mf)
        af[kf][mf] = *(const bf16x8*)&As[cur][(wm * 64 + mf * 16 + (lane & 15)) * 64 + ((kf * 32 + (lane >> 4) * 8) ^ axor)];
#pragma unroll
    for (int kf = 0; kf < 2; ++kf)
#pragma unroll
      for (int nf = 0; nf < 4; ++nf)
        bfr[kf][nf] = *(const bf16x8*)&Bs[cur][(wn * 64 + nf * 16 + (lane & 15)) * 64 + ((kf * 32 + (lane >> 4) * 8) ^ axor)];
#pragma unroll
    for (int mf = 0; mf < 4; ++mf)
#pragma unroll
      for (int nf = 0; nf < 4; ++nf) {
        acc[mf][nf] = __builtin_amdgcn_mfma_f32_16x16x32_bf16(af[0][mf], bfr[0][nf], acc[mf][nf], 0, 0, 0);
        acc[mf][nf] = __builtin_amdgcn_mfma_f32_16x16x32_bf16(af[1][mf], bfr[1][nf], acc[mf][nf], 0, 0, 0);
      }
    __syncthreads();
    cur ^= 1;
  }

  float* Hb = Ht + (size_t)b * 640 * DD;
#pragma unroll
  for (int mf = 0; mf < 4; ++mf)
#pragma unroll
    for (int nf = 0; nf < 4; ++nf)
#pragma unroll
      for (int r = 0; r < 4; ++r) {
        int row = m0 + wm * 64 + mf * 16 + (lane >> 4) * 4 + r;
        int col = n0 + wn * 64 + nf * 16 + (lane & 15);
        Hb[(size_t)row * DD + col] = acc[mf][nf][r];
      }
}

// ---------------- gemm_h: Hcore = Qpad @ Wcomb^T + fused score ----------------
__global__ __launch_bounds__(256, 2)
void gemm_h(const u16* __restrict__ Q, const float* __restrict__ Ht,
            const int* __restrict__ ids, const u16* __restrict__ Wcomb,
            const float* __restrict__ bf1x, const float* __restrict__ w2,
            const float* __restrict__ mask, float* __restrict__ out) {
  int flat = blockIdx.x;
  int lid = (flat & 7) * 141 + (flat >> 3);
  int n = lid % 6;
  int m = (lid / 6) % 47;
  int b = lid / 282;

  const int m0 = m * 128;
  const int n0 = n * 128;
  const int tid = threadIdx.x;
  const int lane = tid & 63;
  const int wid = tid >> 6;
  const int wm = wid >> 1, wn = wid & 1;

  __shared__ u16 As[2][128 * 64];
  __shared__ u16 Bs[2][128 * 64];
  __shared__ int sids[100];
  __shared__ float pacc[4];
  if (tid < 100) sids[tid] = ids[b * 100 + tid];
  if (tid < 4) pacc[tid] = 0.f;
  __syncthreads();

  const u16* Abase = Q + (size_t)b * MPAD * DD;
  const u16* Bbase = Wcomb + (size_t)b * DD * DD;

  f32x4 acc[4][4] = {};

  const int lrow = lane >> 3;
  const int lcol_s = (((lane & 7) ^ (lrow & 7)) * 8);
  const int axor = (lane & 7) << 3;

  const u16* aptr[4];
  const u16* bptr[4];
#pragma unroll
  for (int j = 0; j < 4; ++j) {
    aptr[j] = Abase + (size_t)(m0 + wid * 32 + j * 8 + lrow) * DD + lcol_s;
    bptr[j] = Bbase + (size_t)(n0 + wid * 32 + j * 8 + lrow) * DD + lcol_s;
  }

#pragma unroll
  for (int j = 0; j < 4; ++j) {
    gload_lds16(aptr[j], &As[0][(wid * 32 + j * 8) * 64]);
    gload_lds16(bptr[j], &Bs[0][(wid * 32 + j * 8) * 64]);
    aptr[j] += 64; bptr[j] += 64;
  }
  __syncthreads();

  int cur = 0;
  for (int kt = 0; kt < 12; ++kt) {
    if (kt < 11) {
#pragma unroll
      for (int j = 0; j < 4; ++j) {
        gload_lds16(aptr[j], &As[cur ^ 1][(wid * 32 + j * 8) * 64]);
        gload_lds16(bptr[j], &Bs[cur ^ 1][(wid * 32 + j * 8) * 64]);
        aptr[j] += 64; bptr[j] += 64;
      }
    }
    bf16x8 af[2][4], bfr[2][4];
#pragma unroll
    for (int kf = 0; kf < 2; ++kf)
#pragma unroll
      for (int mf = 0; mf < 4; ++mf)
        af[kf][mf] = *(const bf16x8*)&As[cur][(wm * 64 + mf * 16 + (lane & 15)) * 64 + ((kf * 32 + (lane >> 4) * 8) ^ axor)];
#pragma unroll
    for (int kf = 0; kf < 2; ++kf)
#pragma unroll
      for (int nf = 0; nf < 4; ++nf)
        bfr[kf][nf] = *(const bf16x8*)&Bs[cur][(wn * 64 + nf * 16 + (lane & 15)) * 64 + ((kf * 32 + (lane >> 4) * 8) ^ axor)];
#pragma unroll
    for (int mf = 0; mf < 4; ++mf)
#pragma unroll
      for (int nf = 0; nf < 4; ++nf) {
        acc[mf][nf] = __builtin_amdgcn_mfma_f32_16x16x32_bf16(af[0][mf], bfr[0][nf], acc[mf][nf], 0, 0, 0);
        acc[mf][nf] = __builtin_amdgcn_mfma_f32_16x16x32_bf16(af[1][mf], bfr[1][nf], acc[mf][nf], 0, 0, 0);
      }
    __syncthreads();
    cur ^= 1;
  }

  // fused score epilogue: H = Hcore + Ht[gather] + bf1x[b]
  float b1v[4], w2v[4];
  int cbase = n0 + wn * 64 + (lane & 15);
#pragma unroll
  for (int nf = 0; nf < 4; ++nf) {
    b1v[nf] = bf1x[b * DD + cbase + nf * 16];
    w2v[nf] = w2[cbase + nf * 16];
  }
  const float* Hb = Ht + (size_t)b * 640 * DD;
  const int pfirst = m0 / 60;
#pragma unroll
  for (int mf = 0; mf < 4; ++mf)
#pragma unroll
    for (int r = 0; r < 4; ++r) {
      int row = m0 + wm * 64 + mf * 16 + (lane >> 4) * 4 + r;
      if (row < 6000) {
        int p = (unsigned)row / 60u;
        int tok = row - p * 60;
        const float* htrow = Hb + (size_t)(sids[p] * 60 + tok) * DD + cbase;
        float s = 0.f;
#pragma unroll
        for (int nf = 0; nf < 4; ++nf)
          s += fmaxf(acc[mf][nf][r] + htrow[nf * 16] + b1v[nf], 0.f) * w2v[nf];
        s += __shfl_xor(s, 1);
        s += __shfl_xor(s, 2);
        s += __shfl_xor(s, 4);
        s += __shfl_xor(s, 8);
        if ((lane & 15) == 0) {
          float mk = mask[((size_t)b * 100 + p) * 60 + tok];
          atomicAdd(&pacc[p - pfirst], mk * s);
        }
      }
    }
  __syncthreads();
  int plast = (m0 + 127 < 6000 ? m0 + 127 : 5999) / 60;
  if (tid <= plast - pfirst)
    atomicAdd(out + b * 100 + pfirst + tid, pacc[tid]);
}

// ---------------- launch ----------------
extern "C" void kernel_launch(void* const* d_in, const int* in_sizes, int n_in,
                              void* d_out, int out_size, void* d_ws, size_t ws_size,
                              hipStream_t stream) {
  const float* answer = (const float*)d_in[0];
  const float* qps    = (const float*)d_in[1];
  const float* mask   = (const float*)d_in[2];
  const int*   tids   = (const int*)d_in[3];
  const float* Wp     = (const float*)d_in[4];
  const float* bp     = (const float*)d_in[5];
  const float* Wt     = (const float*)d_in[6];
  const float* bt     = (const float*)d_in[7];
  const float* Wf1    = (const float*)d_in[8];
  const float* bf1    = (const float*)d_in[9];
  const float* Wf2    = (const float*)d_in[10];
  const float* bf2    = (const float*)d_in[11];
  float* out = (float*)d_out;

  char* ws = (char*)d_ws;
  // region layout (bytes); total 102,027,264
  u16* Qpad  = (u16*)(ws + 0);            // 36,962,304
  u16* ts    = (u16*)(ws + 36962304);     // 36,962,304
  u16* tmax  = (u16*)(ws + 73924608);     //  3,686,400
  float* Ht  = (float*)(ws + 77611008);   //  7,864,320
  u16* Wtb   = (u16*)(ws + 85475328);     //  4,718,592
  u16* WpbT  = (u16*)(ws + 90193920);     //  4,718,592
  u16* Wcomb = (u16*)(ws + 94912512);     //  4,718,592
  u16* Wf1b  = (u16*)(ws + 99631104);     //  2,359,296
  float* cp  = (float*)(ws + 101990400);  //     12,288
  float* ct  = (float*)(ws + 102002688);  //     12,288
  float* bf1x= (float*)(ws + 102014976);  //     12,288

  prep_all<<<12866, 256, 0, stream>>>(qps, (uint4*)Qpad, answer, Wp, Wt, Wtb, WpbT,
                                      Wf1, (uint4*)Wf1b, bp, bt, cp, ct,
                                      mask, bf2, out);

  gemm_ts<<<1128, 256, 0, stream>>>(Qpad, Wtb, ct, ts);

  gemm_wc<<<144, 256, 0, stream>>>(Wf1b, WpbT, Wcomb);

  prep2<<<768, 256, 0, stream>>>(Wf1, cp, bf1, bf1x);

  table_max_kernel<<<720, 256, 0, stream>>>(ts, tids, tmax);

  gemm_t<<<120, 256, 0, stream>>>(tmax, Wf1b, Ht);

  gemm_h<<<1128, 256, 0, stream>>>(Qpad, Ht, tids, Wcomb, bf1x, Wf2, mask, out);
}